// Round 1
// baseline (120.804 us; speedup 1.0000x reference)
//
#include <hip/hip_runtime.h>

#define N_POS 4096
#define BH 16  // B * HEADS

// ---------------- K1: qkv projection ----------------
// qkv[b][o][i] = sum_c w_qkv[o][c] * x[b][c][i]
// One block = (b, o, 256-wide i chunk). w row is wave-uniform -> scalar loads.
__global__ __launch_bounds__(256) void qkv_proj(const float* __restrict__ x,
                                                const float* __restrict__ w_qkv,
                                                float* __restrict__ qbuf,
                                                float* __restrict__ kvbuf) {
    int blk = blockIdx.x;
    int ic   = blk & 15;
    int rest = blk >> 4;
    int o = rest % 48;
    int b = rest / 48;
    int i = ic * 256 + threadIdx.x;
    const float* wrow = w_qkv + o * 64;
    const float* xb   = x + ((size_t)b * 64) * N_POS + i;
    float acc = 0.f;
#pragma unroll
    for (int c = 0; c < 64; ++c)
        acc = fmaf(wrow[c], xb[(size_t)c * N_POS], acc);

    if (o < 16) {
        int h = o >> 2, d = o & 3;
        qbuf[(((size_t)(b * 4 + h)) * N_POS + i) * 4 + d] = acc * 0.5f;  // fold scale
    } else if (o < 32) {
        int oo = o - 16, h = oo >> 2, d = oo & 3;
        kvbuf[(((size_t)(b * 4 + h)) * N_POS + i) * 8 + d] = acc;
    } else {
        int oo = o - 32, h = oo >> 2, d = oo & 3;
        kvbuf[(((size_t)(b * 4 + h)) * N_POS + i) * 8 + 4 + d] = acc;
    }
}

// ---------------- K2: flash attention partials (max-free softmax) ----------------
// grid = 16 bh * 4 qtiles * 8 jslices = 512 blocks, 256 threads.
// Each thread owns RQ=4 q positions; block stages its 512-j KV slice in LDS once.
__global__ __launch_bounds__(256) void attn_partial(const float* __restrict__ qbuf,
                                                    const float* __restrict__ kvbuf,
                                                    float4* __restrict__ pacc,
                                                    float* __restrict__ pl) {
    __shared__ float4 kvl[1024];  // 512 j * (k4 + v4) = 16 KB
    int blk = blockIdx.x;
    int js = blk & 7;
    int qt = (blk >> 3) & 3;
    int bh = blk >> 5;

    const float4* src = (const float4*)kvbuf + ((size_t)bh * N_POS + js * 512) * 2;
#pragma unroll
    for (int r = 0; r < 4; ++r)
        kvl[threadIdx.x + r * 256] = src[threadIdx.x + r * 256];
    __syncthreads();

    const float4* q4 = (const float4*)qbuf + (size_t)bh * N_POS + qt * 1024 + threadIdx.x;
    float4 q[4], acc[4];
    float  l[4];
#pragma unroll
    for (int r = 0; r < 4; ++r) {
        q[r] = q4[r * 256];
        acc[r] = make_float4(0.f, 0.f, 0.f, 0.f);
        l[r] = 0.f;
    }

#pragma unroll 4
    for (int j = 0; j < 512; ++j) {
        float4 k = kvl[2 * j];
        float4 v = kvl[2 * j + 1];
#pragma unroll
        for (int r = 0; r < 4; ++r) {
            float s = fmaf(q[r].w, k.w, fmaf(q[r].z, k.z, fmaf(q[r].y, k.y, q[r].x * k.x)));
            float p = __expf(s);
            l[r] += p;
            acc[r].x = fmaf(p, v.x, acc[r].x);
            acc[r].y = fmaf(p, v.y, acc[r].y);
            acc[r].z = fmaf(p, v.z, acc[r].z);
            acc[r].w = fmaf(p, v.w, acc[r].w);
        }
    }

    size_t base = (size_t)js * (BH * N_POS) + (size_t)bh * N_POS + qt * 1024 + threadIdx.x;
#pragma unroll
    for (int r = 0; r < 4; ++r) {
        pacc[base + r * 256] = acc[r];
        pl[base + r * 256]   = l[r];
    }
}

// ---------------- K3: combine partials + output projection + bias ----------------
// one thread per (b, i): gather 8 j-slice partials per head, normalize,
// then y[b][c][i] = b_out[c] + sum_hd w_out[c][hd] * out[hd]
__global__ __launch_bounds__(256) void combine_proj(const float4* __restrict__ pacc,
                                                    const float* __restrict__ pl,
                                                    const float* __restrict__ w_out,
                                                    const float* __restrict__ b_out,
                                                    float* __restrict__ y) {
    int gi = blockIdx.x * 256 + threadIdx.x;  // b*4096 + i
    int b = gi >> 12;
    int i = gi & 4095;

    float o[16];
#pragma unroll
    for (int h = 0; h < 4; ++h) {
        float ax = 0.f, ay = 0.f, az = 0.f, aw = 0.f, l = 0.f;
#pragma unroll
        for (int js = 0; js < 8; ++js) {
            size_t idx = (size_t)js * (BH * N_POS) + (size_t)(b * 4 + h) * N_POS + i;
            float4 t = pacc[idx];
            ax += t.x; ay += t.y; az += t.z; aw += t.w;
            l += pl[idx];
        }
        float inv = 1.0f / l;
        o[h * 4 + 0] = ax * inv;
        o[h * 4 + 1] = ay * inv;
        o[h * 4 + 2] = az * inv;
        o[h * 4 + 3] = aw * inv;
    }

    float* yb = y + (size_t)b * 64 * N_POS + i;
#pragma unroll
    for (int c = 0; c < 64; ++c) {
        const float* wr = w_out + c * 16;
        float s = b_out[c];
#pragma unroll
        for (int t = 0; t < 16; ++t) s = fmaf(wr[t], o[t], s);
        yb[(size_t)c * N_POS] = s;
    }
}

extern "C" void kernel_launch(void* const* d_in, const int* in_sizes, int n_in,
                              void* d_out, int out_size, void* d_ws, size_t ws_size,
                              hipStream_t stream) {
    const float* x     = (const float*)d_in[0];
    const float* w_qkv = (const float*)d_in[1];
    const float* w_out = (const float*)d_in[2];
    const float* b_out = (const float*)d_in[3];
    float* y = (float*)d_out;

    // workspace layout (floats):
    // qbuf: [16][4096][4]          = 262144
    // kvbuf:[16][4096][8]          = 524288
    // pacc: [8][16][4096] float4   = 2097152 floats
    // pl:   [8][16][4096]          = 524288
    float* w = (float*)d_ws;
    float*  qbuf  = w;
    float*  kvbuf = w + 262144;
    float4* pacc  = (float4*)(w + 262144 + 524288);
    float*  pl    = w + 262144 + 524288 + 2097152;

    qkv_proj<<<4 * 48 * 16, 256, 0, stream>>>(x, w_qkv, qbuf, kvbuf);
    attn_partial<<<512, 256, 0, stream>>>(qbuf, kvbuf, pacc, pl);
    combine_proj<<<64, 256, 0, stream>>>(pacc, pl, w_out, b_out, y);
}